// Round 2
// baseline (242.415 us; speedup 1.0000x reference)
//
#include <hip/hip_runtime.h>
#include <math.h>

#define NSAMP 32
#define MFEAT 30
#define XPAD  36                 // LDS row stride in floats
#define SQRT3 1.7320508075688772f

__device__ __forceinline__ float rdlane(float v, int l) {
    return __int_as_float(__builtin_amdgcn_readlane(__float_as_int(v), l));
}

__global__ __launch_bounds__(128, 6) void tmk_kernel(
    const float* __restrict__ aug,     // (32, n_loc, 31)
    const float* __restrict__ scales,  // (n_loc)
    const float* __restrict__ nug,     // (n_loc)
    const float* __restrict__ frac,    // (1)
    const int*   __restrict__ bidx,    // (n_loc)
    const float* __restrict__ thq,     // (1)
    const float* __restrict__ sigp,    // (2)
    const float* __restrict__ lens,    // (1)
    float* __restrict__ out,
    int n_loc)
{
    __shared__ __align__(16) float X[2][NSAMP * XPAD];   // per-wave feature tile, reused for L transpose
    __shared__ float SQ[2][NSAMP];
    __shared__ float SC[NSAMP];                          // shared scale table (uniform across locations)

    const int tid  = threadIdx.x;
    const int wv   = tid >> 6;        // wave in block: 0 or 1
    const int lane = tid & 63;
    const int j    = lane & 31;
    const int ih   = lane >> 5;       // row parity handled by this half-wave

    int loc = blockIdx.x * 2 + wv;
    if (loc >= n_loc) loc = n_loc - 1;   // clamp (duplicate work writes identical values)

    // ---- uniform scalars + scale table ----
    const float a_s   = -0.5f * __expf(thq[0]);
    const float invls = 1.0f / (__expf(lens[0]) * SQRT3);
    if (tid < MFEAT) SC[tid] = __expf(a_s * (float)(tid + 1)) * invls;
    __syncthreads();

    // ---- stage scaled features: X[s][k] = nan_to_0(aug[s,loc,1+k]) * SC[k] ----
    float* Xw = X[wv];
    {
        const float* bp = aug + (size_t)loc * 31 + 1;
        const size_t srow = (size_t)n_loc * 31;
#pragma unroll
        for (int it = 0; it < 15; ++it) {            // 15*64 = 960 = 32*30
            unsigned t = (unsigned)lane + it * 64u;
            unsigned s = t / MFEAT;
            unsigned k = t - s * MFEAT;
            float v = bp[(size_t)s * srow + k];
            v = (v != v) ? 0.0f : v;                 // isnan -> 0
            Xw[s * XPAD + k] = v * SC[k];
        }
        // zero-pad cols 30,31 so float4 chunk 7 reads zeros
        Xw[(lane & 31) * XPAD + MFEAT + ih] = 0.0f;
    }
    __syncthreads();

    // ---- per-lane row j in registers + squared norm ----
    float xc[32];
#pragma unroll
    for (int c = 0; c < 8; ++c) {
        float4 v = *reinterpret_cast<const float4*>(&Xw[j * XPAD + 4 * c]);
        xc[4 * c + 0] = v.x; xc[4 * c + 1] = v.y;
        xc[4 * c + 2] = v.z; xc[4 * c + 3] = v.w;
    }
    float sq_own;
    {
        float s0 = 0.f, s1 = 0.f, s2 = 0.f, s3 = 0.f;
#pragma unroll
        for (int c = 0; c < 8; ++c) {
            s0 = fmaf(xc[4 * c + 0], xc[4 * c + 0], s0);
            s1 = fmaf(xc[4 * c + 1], xc[4 * c + 1], s1);
            s2 = fmaf(xc[4 * c + 2], xc[4 * c + 2], s2);
            s3 = fmaf(xc[4 * c + 3], xc[4 * c + 3], s3);
        }
        sq_own = (s0 + s1) + (s2 + s3);
    }
    if (lane < 32) SQ[wv][j] = sq_own;
    __syncthreads();

    // ---- per-location coefficient ----
    const float fr  = frac[0];
    const float scl = scales[loc];
    const float nm  = nug[loc];
    const float sig = __expf(sigp[0] + sigp[1] * __logf(scl));
    const float coef = fr * sig * sig / nm;
    const bool  bz   = (bidx[loc] == 0);
    const float sqj  = sq_own;

    // ---- Gram + matern epilogue; store g coalesced; build Cholesky row in registers ----
    const size_t gbase = (size_t)loc * 1024;
    float* gout = out + gbase;
    float av[32];                        // full row j of G (both halves identical after shfl)
#pragma unroll
    for (int r = 0; r < 16; ++r) {
        const int i = 2 * r + ih;
        float a0 = 0.f, a1 = 0.f, a2 = 0.f, a3 = 0.f;
#pragma unroll
        for (int c = 0; c < 8; ++c) {
            float4 v = *reinterpret_cast<const float4*>(&Xw[i * XPAD + 4 * c]); // broadcast read
            a0 = fmaf(v.x, xc[4 * c + 0], a0);
            a1 = fmaf(v.y, xc[4 * c + 1], a1);
            a2 = fmaf(v.z, xc[4 * c + 2], a2);
            a3 = fmaf(v.w, xc[4 * c + 3], a3);
        }
        float dot = (a0 + a1) + (a2 + a3);
        float d2  = fmaxf(SQ[wv][i] + sqj - 2.f * dot, 0.f);   // exact 0 on diagonal
        float s3d = SQRT3 * sqrtf(d2);
        float nl  = (1.f + s3d) * __expf(-s3d);
        float dg  = (i == j) ? 1.f : 0.f;
        float gv  = fmaf(coef, nl, dg);
        if (bz) gv = dg;
        gout[64 * r + lane] = gv;            // == gout[i*32 + j], coalesced
        float pg = __shfl_xor(gv, 32, 64);   // partner half's row (other parity)
        av[2 * r + 0] = (ih == 0) ? gv : pg; // static indices (no scratch)
        av[2 * r + 1] = (ih == 0) ? pg : gv;
    }

    // ---- register Cholesky: lane i owns row i (halves duplicate, harmless) ----
#pragma unroll
    for (int k = 0; k < 32; ++k) {
        float dinv = __frsqrt_rn(rdlane(av[k], k));    // v_rsq, 1 instr
        float lik  = av[k] * dinv;                     // L[i][k] (valid for i>=k)
        av[k] = lik;
#pragma unroll
        for (int jj = k + 1; jj < 32; ++jj) {
            av[jj] = fmaf(-lik, rdlane(lik, jj), av[jj]);  // A[i][jj] -= L[i][k]*L[jj][k]
        }
    }
    __syncthreads();   // all Gram X-reads done; X reusable

    // ---- write masked L rows into X (transpose buffer), then coalesced store ----
    if (lane < 32) {
#pragma unroll
        for (int c = 0; c < 8; ++c) {
            float4 w;
            w.x = (4 * c + 0 <= j) ? av[4 * c + 0] : 0.f;
            w.y = (4 * c + 1 <= j) ? av[4 * c + 1] : 0.f;
            w.z = (4 * c + 2 <= j) ? av[4 * c + 2] : 0.f;
            w.w = (4 * c + 3 <= j) ? av[4 * c + 3] : 0.f;
            *reinterpret_cast<float4*>(&Xw[j * XPAD + 4 * c]) = w;
        }
    }
    __syncthreads();

    float* lout = out + (size_t)n_loc * 1024 + gbase;
#pragma unroll
    for (int r = 0; r < 16; ++r) {
        lout[64 * r + lane] = Xw[(2 * r + ih) * XPAD + j];
    }

    if (lane == 0) out[(size_t)n_loc * 2048 + loc] = nm;
}

extern "C" void kernel_launch(void* const* d_in, const int* in_sizes, int n_in,
                              void* d_out, int out_size, void* d_ws, size_t ws_size,
                              hipStream_t stream) {
    const float* aug    = (const float*)d_in[0];
    const float* scales = (const float*)d_in[1];
    const float* nug    = (const float*)d_in[2];
    const float* frac   = (const float*)d_in[3];
    const int*   bidx   = (const int*)  d_in[4];
    const float* thq    = (const float*)d_in[5];
    const float* sigp   = (const float*)d_in[6];
    const float* lens   = (const float*)d_in[7];
    const int n_loc = in_sizes[1];

    const int nblk = (n_loc + 1) / 2;
    tmk_kernel<<<nblk, 128, 0, stream>>>(aug, scales, nug, frac, bidx, thq,
                                         sigp, lens, (float*)d_out, n_loc);
}

// Round 3
// 144.252 us; speedup vs baseline: 1.6805x; 1.6805x over previous
//
#include <hip/hip_runtime.h>
#include <math.h>

#define NSAMP 32
#define MFEAT 30
#define XPAD  36                  // floats per LDS row: 144 B, 16B-aligned
#define SQRT3 1.7320508075688772f

// broadcast lane L (0..31) within each 32-lane half: ds_swizzle BitMode,
// offset = (xor<<10)|(or<<5)|(and), and=0 or=L xor=0  ->  L<<5
template<int L>
__device__ __forceinline__ float bcast32(float v) {
    return __int_as_float(__builtin_amdgcn_ds_swizzle(__float_as_int(v), (L << 5)));
}

template<int K, int JJ>
struct Upd {
    static __device__ __forceinline__ void run(float* av, float lik) {
        float b = bcast32<JJ>(lik);                 // L[jj][k] of this half's loc
        av[JJ] = fmaf(-lik, b, av[JJ]);
        Upd<K, JJ + 1>::run(av, lik);
    }
};
template<int K>
struct Upd<K, NSAMP> {
    static __device__ __forceinline__ void run(float*, float) {}
};

template<int K>
struct Chol {
    static __device__ __forceinline__ void run(float* av) {
        float diag = bcast32<K>(av[K]);             // diag from lane K of this half
        float lik  = av[K] * __frsqrt_rn(diag);     // L[i][k] (valid for i>=k)
        av[K] = lik;
        Upd<K, K + 1>::run(av, lik);
        Chol<K + 1>::run(av);
    }
};
template<>
struct Chol<NSAMP> { static __device__ __forceinline__ void run(float*) {} };

__global__ __launch_bounds__(64, 4) void tmk_kernel(
    const float* __restrict__ aug,     // (32, n_loc, 31)
    const float* __restrict__ scales,  // (n_loc)
    const float* __restrict__ nug,     // (n_loc)
    const float* __restrict__ frac,    // (1)
    const int*   __restrict__ bidx,    // (n_loc)
    const float* __restrict__ thq,     // (1)
    const float* __restrict__ sigp,    // (2)
    const float* __restrict__ lens,    // (1)
    float* __restrict__ out,
    int n_loc)
{
    __shared__ __align__(16) float X[2][NSAMP * XPAD];   // one feature tile per half-wave's location
    __shared__ float SQ[2][NSAMP];
    __shared__ float SC[32];

    const int lane = threadIdx.x;       // 64-thread block = 1 wave
    const int j    = lane & 31;         // sample row owned by this lane
    const int h    = lane >> 5;         // which of the 2 locations

    const int locA = blockIdx.x * 2;
    int locB = locA + 1; if (locB >= n_loc) locB = n_loc - 1;
    const int loc = h ? locB : locA;

    // ---- uniform scalars + per-feature scale table ----
    const float a_s   = -0.5f * __expf(thq[0]);
    const float invls = 1.0f / (__expf(lens[0]) * SQRT3);
    if (lane < MFEAT) SC[lane] = __expf(a_s * (float)(lane + 1)) * invls;
    __syncthreads();

    // ---- stage scaled features for both locations: X[h][s][k] = nan_to_0(aug[s,loc,1+k]) * SC[k] ----
    {
        const size_t srow = (size_t)n_loc * 31;
#pragma unroll
        for (int it = 0; it < 30; ++it) {           // 30*64 = 1920 = 2*32*30
            const int hh = (it >= 15);              // compile-time per iteration
            const int t  = it * 64 + lane - hh * 960;
            const int s  = t / MFEAT;
            const int k  = t - s * MFEAT;
            const int lc = hh ? locB : locA;
            float v = aug[(size_t)s * srow + (size_t)lc * 31 + 1 + k];
            v = (v != v) ? 0.0f : v;                // isnan -> 0
            X[hh][s * XPAD + k] = v * SC[k];
        }
        // zero-pad cols 30,31 so float4 chunk 7 reads zeros
        X[h][j * XPAD + 30] = 0.0f;
        X[h][j * XPAD + 31] = 0.0f;
    }
    __syncthreads();

    // ---- per-lane sample row j in registers + squared norm ----
    float xc[32];
#pragma unroll
    for (int c = 0; c < 8; ++c) {
        float4 v = *reinterpret_cast<const float4*>(&X[h][j * XPAD + 4 * c]);
        xc[4 * c + 0] = v.x; xc[4 * c + 1] = v.y;
        xc[4 * c + 2] = v.z; xc[4 * c + 3] = v.w;
    }
    float sq_own;
    {
        float s0 = 0.f, s1 = 0.f, s2 = 0.f, s3 = 0.f;
#pragma unroll
        for (int c = 0; c < 8; ++c) {
            s0 = fmaf(xc[4 * c + 0], xc[4 * c + 0], s0);
            s1 = fmaf(xc[4 * c + 1], xc[4 * c + 1], s1);
            s2 = fmaf(xc[4 * c + 2], xc[4 * c + 2], s2);
            s3 = fmaf(xc[4 * c + 3], xc[4 * c + 3], s3);
        }
        sq_own = (s0 + s1) + (s2 + s3);
    }
    SQ[h][j] = sq_own;
    __syncthreads();

    // ---- per-location coefficient ----
    const float scl = scales[loc];
    const float nm  = nug[loc];
    const float sig = __expf(sigp[0] + sigp[1] * __logf(scl));
    const float coef = frac[0] * sig * sig / nm;
    const bool  bz   = (bidx[loc] == 0);

    // ---- Gram rows + matern epilogue; lane j accumulates full row j (== col j by symmetry) ----
    const size_t gbase = (size_t)loc * 1024;
    float* gout = out + gbase;
    float av[32];
#pragma unroll
    for (int i = 0; i < 32; ++i) {
        float a0 = 0.f, a1 = 0.f, a2 = 0.f, a3 = 0.f;
#pragma unroll
        for (int c = 0; c < 8; ++c) {
            // broadcast read of sample row i (one address per half)
            float4 v = *reinterpret_cast<const float4*>(&X[h][i * XPAD + 4 * c]);
            a0 = fmaf(v.x, xc[4 * c + 0], a0);
            a1 = fmaf(v.y, xc[4 * c + 1], a1);
            a2 = fmaf(v.z, xc[4 * c + 2], a2);
            a3 = fmaf(v.w, xc[4 * c + 3], a3);
        }
        float dot = (a0 + a1) + (a2 + a3);
        float d2  = fmaxf(SQ[h][i] + sq_own - 2.f * dot, 0.f);   // exactly 0 on diagonal
        float s3d = SQRT3 * sqrtf(d2);
        float nl  = (1.f + s3d) * __expf(-s3d);
        float dg  = (i == j) ? 1.f : 0.f;
        float gv  = fmaf(coef, nl, dg);
        if (bz) gv = dg;
        av[i] = gv;
        gout[i * 32 + j] = gv;       // coalesced: 128B per half per instr
    }

    // ---- register Cholesky (serves both locations; lane j = row j of its loc) ----
    Chol<0>::run(av);

    // ---- masked L row store: 8 float4 per lane; lines completed within the wave ----
    float* lrow = out + (size_t)n_loc * 1024 + gbase + (size_t)j * 32;
#pragma unroll
    for (int c = 0; c < 8; ++c) {
        float4 w;
        w.x = (4 * c + 0 <= j) ? av[4 * c + 0] : 0.f;
        w.y = (4 * c + 1 <= j) ? av[4 * c + 1] : 0.f;
        w.z = (4 * c + 2 <= j) ? av[4 * c + 2] : 0.f;
        w.w = (4 * c + 3 <= j) ? av[4 * c + 3] : 0.f;
        *reinterpret_cast<float4*>(&lrow[4 * c]) = w;
    }

    if (j == 0) out[(size_t)n_loc * 2048 + loc] = nm;
}

extern "C" void kernel_launch(void* const* d_in, const int* in_sizes, int n_in,
                              void* d_out, int out_size, void* d_ws, size_t ws_size,
                              hipStream_t stream) {
    const float* aug    = (const float*)d_in[0];
    const float* scales = (const float*)d_in[1];
    const float* nug    = (const float*)d_in[2];
    const float* frac   = (const float*)d_in[3];
    const int*   bidx   = (const int*)  d_in[4];
    const float* thq    = (const float*)d_in[5];
    const float* sigp   = (const float*)d_in[6];
    const float* lens   = (const float*)d_in[7];
    const int n_loc = in_sizes[1];

    const int nblk = (n_loc + 1) / 2;
    tmk_kernel<<<nblk, 64, 0, stream>>>(aug, scales, nug, frac, bidx, thq,
                                        sigp, lens, (float*)d_out, n_loc);
}